// Round 1
// baseline (10236.900 us; speedup 1.0000x reference)
//
#include <hip/hip_runtime.h>

#define N_USERS 100000
#define N_ITEMS 50000
#define N_TOPICS 1000
#define N_NODES (N_USERS + N_ITEMS + N_TOPICS)   // 151000
#define DIM 64
#define NNZ 4000000
#define BATCH 16384

// ---------------------------------------------------------------------------
// Build X0 = concat(user_w, item_w, topic_w). One float4 (4 dims) per thread.
// ---------------------------------------------------------------------------
__global__ void concat_init(const float4* __restrict__ uw,
                            const float4* __restrict__ iw,
                            const float4* __restrict__ tw,
                            float4* __restrict__ x0) {
    int tid = blockIdx.x * blockDim.x + threadIdx.x;   // node*16 + q
    const int total = N_NODES * (DIM / 4);
    if (tid >= total) return;
    int node = tid >> 4;
    int q = tid & 15;
    float4 v;
    if (node < N_USERS)                v = uw[node * 16 + q];
    else if (node < N_USERS + N_ITEMS) v = iw[(node - N_USERS) * 16 + q];
    else                               v = tw[(node - N_USERS - N_ITEMS) * 16 + q];
    x0[tid] = v;
}

// ---------------------------------------------------------------------------
// Batch accumulator init: acc_b[b]       = user_w[users[b]]   (layer-0 emb)
//                         acc_b[B + b]   = item_w[items[b]]
// Layout: [2*BATCH, 64] as float4 rows of 16.
// ---------------------------------------------------------------------------
__global__ void batch_init(const float4* __restrict__ uw,
                           const float4* __restrict__ iw,
                           const int* __restrict__ users,
                           const int* __restrict__ items,
                           float4* __restrict__ accb) {
    int tid = blockIdx.x * blockDim.x + threadIdx.x;   // row*16 + q
    const int total = 2 * BATCH * (DIM / 4);
    if (tid >= total) return;
    int r = tid >> 4;
    int q = tid & 15;
    float4 v;
    if (r < BATCH) v = uw[(long long)users[r] * 16 + q];
    else           v = iw[(long long)items[r - BATCH] * 16 + q];
    accb[tid] = v;
}

// ---------------------------------------------------------------------------
// Batch accumulator add from full node table: accb[b] += emb[node_of(b)]
// ---------------------------------------------------------------------------
__global__ void batch_add(const float4* __restrict__ emb,
                          const int* __restrict__ users,
                          const int* __restrict__ items,
                          float4* __restrict__ accb) {
    int tid = blockIdx.x * blockDim.x + threadIdx.x;
    const int total = 2 * BATCH * (DIM / 4);
    if (tid >= total) return;
    int r = tid >> 4;
    int q = tid & 15;
    int node = (r < BATCH) ? users[r] : (N_USERS + items[r - BATCH]);
    float4 v = emb[(long long)node * 16 + q];
    float4 a = accb[tid];
    a.x += v.x; a.y += v.y; a.z += v.z; a.w += v.w;
    accb[tid] = a;
}

// ---------------------------------------------------------------------------
// SpMM: y[row[e]] += vals[e] * x[col[e]], 16 threads/edge (float4 each).
// Within a wave: 4 edges; each 16-lane group reads a contiguous 256B x-row.
// ---------------------------------------------------------------------------
__global__ void spmm_atomic(const float* __restrict__ vals,
                            const int* __restrict__ row,
                            const int* __restrict__ col,
                            const float4* __restrict__ x,
                            float* __restrict__ y) {
    int tid = blockIdx.x * blockDim.x + threadIdx.x;   // < NNZ*16, fits int32
    if (tid >= NNZ * 16) return;
    int e = tid >> 4;
    int q = tid & 15;
    int r = row[e];
    int c = col[e];
    float v = vals[e];
    float4 xv = x[(long long)c * 16 + q];
    float* yp = y + (long long)r * 64 + q * 4;
    atomicAdd(yp + 0, v * xv.x);
    atomicAdd(yp + 1, v * xv.y);
    atomicAdd(yp + 2, v * xv.z);
    atomicAdd(yp + 3, v * xv.w);
}

// ---------------------------------------------------------------------------
// Final dot: out[b] = (accb[b] . accb[BATCH+b]) / 16   (the /4 per side)
// One 64-lane wave per batch element; 4 waves per 256-thread block.
// ---------------------------------------------------------------------------
__global__ void final_dot(const float* __restrict__ accb,
                          float* __restrict__ out) {
    int b = blockIdx.x * 4 + (threadIdx.x >> 6);
    int lane = threadIdx.x & 63;
    if (b >= BATCH) return;
    float pu = accb[(long long)b * 64 + lane];
    float pi = accb[(long long)(BATCH + b) * 64 + lane];
    float p = pu * pi;
    #pragma unroll
    for (int off = 32; off > 0; off >>= 1)
        p += __shfl_down(p, off, 64);
    if (lane == 0) out[b] = p * (1.0f / 16.0f);
}

extern "C" void kernel_launch(void* const* d_in, const int* in_sizes, int n_in,
                              void* d_out, int out_size, void* d_ws, size_t ws_size,
                              hipStream_t stream) {
    const float* uw   = (const float*)d_in[0];
    const float* iw   = (const float*)d_in[1];
    const float* tw   = (const float*)d_in[2];
    const float* vals = (const float*)d_in[3];
    const int*   row  = (const int*)d_in[4];
    const int*   col  = (const int*)d_in[5];
    const int*   users= (const int*)d_in[6];
    const int*   items= (const int*)d_in[7];
    float* out = (float*)d_out;

    float* ws = (float*)d_ws;
    const size_t NODE_F = (size_t)N_NODES * DIM;       // 9,664,000 floats
    float* A    = ws;                                  // full emb ping
    float* B    = ws + NODE_F;                         // full emb pong
    float* ACCB = ws + 2 * NODE_F;                     // [2*BATCH, 64]

    const int node_v4  = N_NODES * (DIM / 4);          // 2,416,000
    const int batch_v4 = 2 * BATCH * (DIM / 4);        // 524,288

    // Layer-0 embedding into A; batch accumulator init from raw weights.
    concat_init<<<(node_v4 + 255) / 256, 256, 0, stream>>>(
        (const float4*)uw, (const float4*)iw, (const float4*)tw, (float4*)A);
    batch_init<<<(batch_v4 + 255) / 256, 256, 0, stream>>>(
        (const float4*)uw, (const float4*)iw, users, items, (float4*)ACCB);

    float* cur = A;
    float* nxt = B;
    for (int l = 0; l < 3; ++l) {
        hipMemsetAsync(nxt, 0, NODE_F * sizeof(float), stream);
        spmm_atomic<<<(NNZ * 16) / 256, 256, 0, stream>>>(
            vals, row, col, (const float4*)cur, nxt);
        batch_add<<<(batch_v4 + 255) / 256, 256, 0, stream>>>(
            (const float4*)nxt, users, items, (float4*)ACCB);
        float* t = cur; cur = nxt; nxt = t;
    }

    final_dot<<<(BATCH + 3) / 4, 256, 0, stream>>>(ACCB, out);
}

// Round 2
// 1354.316 us; speedup vs baseline: 7.5587x; 7.5587x over previous
//
#include <hip/hip_runtime.h>

#define N_USERS 100000
#define N_ITEMS 50000
#define N_TOPICS 1000
#define N_NODES (N_USERS + N_ITEMS + N_TOPICS)   // 151000
#define DIM 64
#define NNZ 4000000
#define BATCH 16384

// ---------------------------------------------------------------------------
// Build X0 = concat(user_w, item_w, topic_w). One float4 (4 dims) per thread.
// ---------------------------------------------------------------------------
__global__ void concat_init(const float4* __restrict__ uw,
                            const float4* __restrict__ iw,
                            const float4* __restrict__ tw,
                            float4* __restrict__ x0) {
    int tid = blockIdx.x * blockDim.x + threadIdx.x;   // node*16 + q
    const int total = N_NODES * (DIM / 4);
    if (tid >= total) return;
    int node = tid >> 4;
    int q = tid & 15;
    float4 v;
    if (node < N_USERS)                v = uw[node * 16 + q];
    else if (node < N_USERS + N_ITEMS) v = iw[(node - N_USERS) * 16 + q];
    else                               v = tw[(node - N_USERS - N_ITEMS) * 16 + q];
    x0[tid] = v;
}

// ---------------------------------------------------------------------------
// CSR build step 1: per-row edge histogram (int atomics, low contention).
// ---------------------------------------------------------------------------
__global__ void hist_kernel(const int* __restrict__ row, int* __restrict__ cnt) {
    int e = blockIdx.x * blockDim.x + threadIdx.x;
    if (e >= NNZ) return;
    atomicAdd(&cnt[row[e]], 1);
}

// ---------------------------------------------------------------------------
// CSR build step 2: exclusive prefix scan over cnt -> rowptr, cursor.
// Single workgroup, 1024 threads, wave-shfl scan + cross-wave LDS combine.
// ---------------------------------------------------------------------------
__global__ void scan_kernel(const int* __restrict__ cnt,
                            int* __restrict__ rowptr,
                            int* __restrict__ cursor) {
    __shared__ int wsum[16];
    __shared__ int carry_s;
    const int t = threadIdx.x;
    const int lane = t & 63;
    const int wid = t >> 6;
    if (t == 0) carry_s = 0;
    __syncthreads();
    for (int base = 0; base < N_NODES; base += 1024) {
        int i = base + t;
        int v = (i < N_NODES) ? cnt[i] : 0;
        // inclusive scan within wave
        int x = v;
        #pragma unroll
        for (int off = 1; off < 64; off <<= 1) {
            int y = __shfl_up(x, off, 64);
            if (lane >= off) x += y;
        }
        if (lane == 63) wsum[wid] = x;
        __syncthreads();
        int wbase = 0;
        for (int w = 0; w < wid; ++w) wbase += wsum[w];
        int excl = carry_s + wbase + (x - v);
        if (i < N_NODES) { rowptr[i] = excl; cursor[i] = excl; }
        __syncthreads();
        if (t == 1023) carry_s = excl + v;
        __syncthreads();
    }
    if (t == 0) rowptr[N_NODES] = carry_s;   // == NNZ
}

// ---------------------------------------------------------------------------
// CSR build step 3: scatter edges into row-sorted order (reorder col & vals).
// ---------------------------------------------------------------------------
__global__ void scatter_kernel(const int* __restrict__ row,
                               const int* __restrict__ col,
                               const float* __restrict__ vals,
                               int* __restrict__ cursor,
                               int* __restrict__ ecol,
                               float* __restrict__ eval) {
    int e = blockIdx.x * blockDim.x + threadIdx.x;
    if (e >= NNZ) return;
    int r = row[e];
    int p = atomicAdd(&cursor[r], 1);
    ecol[p] = col[e];
    eval[p] = vals[e];
}

// ---------------------------------------------------------------------------
// SpMM over CSR: one 64-lane wave per row, lane = dim. No atomics.
// y[r][lane] = sum_j eval[j] * x[ecol[j]][lane]
// ---------------------------------------------------------------------------
__global__ void spmm_csr(const int* __restrict__ rowptr,
                         const int* __restrict__ ecol,
                         const float* __restrict__ eval,
                         const float* __restrict__ x,
                         float* __restrict__ y) {
    int r = blockIdx.x * (blockDim.x >> 6) + (threadIdx.x >> 6);
    int lane = threadIdx.x & 63;
    if (r >= N_NODES) return;
    int beg = rowptr[r];
    int end = rowptr[r + 1];
    float acc = 0.0f;
    int j = beg;
    // unroll-by-2: two independent gathers in flight
    for (; j + 1 < end; j += 2) {
        int c0 = ecol[j];
        int c1 = ecol[j + 1];
        float v0 = eval[j];
        float v1 = eval[j + 1];
        float x0 = x[(long long)c0 * 64 + lane];
        float x1 = x[(long long)c1 * 64 + lane];
        acc = fmaf(v0, x0, acc);
        acc = fmaf(v1, x1, acc);
    }
    if (j < end) {
        int c0 = ecol[j];
        float v0 = eval[j];
        acc = fmaf(v0, x[(long long)c0 * 64 + lane], acc);
    }
    y[(long long)r * 64 + lane] = acc;
}

// ---------------------------------------------------------------------------
// Batch accumulator init: accb[b] = user_w[users[b]], accb[B+b] = item_w[items[b]]
// ---------------------------------------------------------------------------
__global__ void batch_init(const float4* __restrict__ uw,
                           const float4* __restrict__ iw,
                           const int* __restrict__ users,
                           const int* __restrict__ items,
                           float4* __restrict__ accb) {
    int tid = blockIdx.x * blockDim.x + threadIdx.x;   // row*16 + q
    const int total = 2 * BATCH * (DIM / 4);
    if (tid >= total) return;
    int r = tid >> 4;
    int q = tid & 15;
    float4 v;
    if (r < BATCH) v = uw[(long long)users[r] * 16 + q];
    else           v = iw[(long long)items[r - BATCH] * 16 + q];
    accb[tid] = v;
}

// ---------------------------------------------------------------------------
// Batch accumulator add from full node table.
// ---------------------------------------------------------------------------
__global__ void batch_add(const float4* __restrict__ emb,
                          const int* __restrict__ users,
                          const int* __restrict__ items,
                          float4* __restrict__ accb) {
    int tid = blockIdx.x * blockDim.x + threadIdx.x;
    const int total = 2 * BATCH * (DIM / 4);
    if (tid >= total) return;
    int r = tid >> 4;
    int q = tid & 15;
    int node = (r < BATCH) ? users[r] : (N_USERS + items[r - BATCH]);
    float4 v = emb[(long long)node * 16 + q];
    float4 a = accb[tid];
    a.x += v.x; a.y += v.y; a.z += v.z; a.w += v.w;
    accb[tid] = a;
}

// ---------------------------------------------------------------------------
// Final dot: out[b] = (accb[b] . accb[BATCH+b]) / 16
// ---------------------------------------------------------------------------
__global__ void final_dot(const float* __restrict__ accb,
                          float* __restrict__ out) {
    int b = blockIdx.x * 4 + (threadIdx.x >> 6);
    int lane = threadIdx.x & 63;
    if (b >= BATCH) return;
    float pu = accb[(long long)b * 64 + lane];
    float pi = accb[(long long)(BATCH + b) * 64 + lane];
    float p = pu * pi;
    #pragma unroll
    for (int off = 32; off > 0; off >>= 1)
        p += __shfl_down(p, off, 64);
    if (lane == 0) out[b] = p * (1.0f / 16.0f);
}

extern "C" void kernel_launch(void* const* d_in, const int* in_sizes, int n_in,
                              void* d_out, int out_size, void* d_ws, size_t ws_size,
                              hipStream_t stream) {
    const float* uw   = (const float*)d_in[0];
    const float* iw   = (const float*)d_in[1];
    const float* tw   = (const float*)d_in[2];
    const float* vals = (const float*)d_in[3];
    const int*   row  = (const int*)d_in[4];
    const int*   col  = (const int*)d_in[5];
    const int*   users= (const int*)d_in[6];
    const int*   items= (const int*)d_in[7];
    float* out = (float*)d_out;

    // ---- workspace layout (all 4-byte elements) ----
    char* ws = (char*)d_ws;
    const size_t NODE_F = (size_t)N_NODES * DIM;       // 9,664,000
    float* A      = (float*)ws;                         ws += NODE_F * 4;
    float* B      = (float*)ws;                         ws += NODE_F * 4;
    float* ACCB   = (float*)ws;                         ws += (size_t)2 * BATCH * DIM * 4;
    int*   cnt    = (int*)ws;                           ws += (size_t)N_NODES * 4;
    int*   rowptr = (int*)ws;                           ws += (size_t)(N_NODES + 1) * 4;
    int*   cursor = (int*)ws;                           ws += (size_t)N_NODES * 4;
    int*   ecol   = (int*)ws;                           ws += (size_t)NNZ * 4;
    float* eval   = (float*)ws;                         ws += (size_t)NNZ * 4;

    const int node_v4  = N_NODES * (DIM / 4);
    const int batch_v4 = 2 * BATCH * (DIM / 4);

    // ---- CSR build (per call; inputs are re-poisoned each launch) ----
    hipMemsetAsync(cnt, 0, (size_t)N_NODES * 4, stream);
    hist_kernel<<<(NNZ + 255) / 256, 256, 0, stream>>>(row, cnt);
    scan_kernel<<<1, 1024, 0, stream>>>(cnt, rowptr, cursor);
    scatter_kernel<<<(NNZ + 255) / 256, 256, 0, stream>>>(row, col, vals,
                                                          cursor, ecol, eval);

    // ---- layer-0 embedding + batch accumulator init ----
    concat_init<<<(node_v4 + 255) / 256, 256, 0, stream>>>(
        (const float4*)uw, (const float4*)iw, (const float4*)tw, (float4*)A);
    batch_init<<<(batch_v4 + 255) / 256, 256, 0, stream>>>(
        (const float4*)uw, (const float4*)iw, users, items, (float4*)ACCB);

    // ---- 3 propagation layers ----
    float* cur = A;
    float* nxt = B;
    const int spmm_blocks = (N_NODES + 3) / 4;   // 4 waves (rows) per 256-block
    for (int l = 0; l < 3; ++l) {
        spmm_csr<<<spmm_blocks, 256, 0, stream>>>(rowptr, ecol, eval, cur, nxt);
        batch_add<<<(batch_v4 + 255) / 256, 256, 0, stream>>>(
            (const float4*)nxt, users, items, (float4*)ACCB);
        float* t = cur; cur = nxt; nxt = t;
    }

    final_dot<<<(BATCH + 3) / 4, 256, 0, stream>>>(ACCB, out);
}

// Round 3
// 993.721 us; speedup vs baseline: 10.3016x; 1.3629x over previous
//
#include <hip/hip_runtime.h>

#define N_USERS 100000
#define N_ITEMS 50000
#define N_TOPICS 1000
#define N_NODES (N_USERS + N_ITEMS + N_TOPICS)   // 151000
#define DIM 64
#define NNZ 4000000
#define BATCH 16384

#define NGRP 8                                    // XCD count heuristic
#define ROWS_PER_GRP ((N_NODES + NGRP - 1) / NGRP)   // 18875
#define SCAN_BLK 1024
#define SCAN_NBLK ((N_NODES + SCAN_BLK - 1) / SCAN_BLK)  // 148

// ---------------------------------------------------------------------------
// Build X0 = concat(user_w, item_w, topic_w). One float4 (4 dims) per thread.
// ---------------------------------------------------------------------------
__global__ void concat_init(const float4* __restrict__ uw,
                            const float4* __restrict__ iw,
                            const float4* __restrict__ tw,
                            float4* __restrict__ x0) {
    int tid = blockIdx.x * blockDim.x + threadIdx.x;   // node*16 + q
    const int total = N_NODES * (DIM / 4);
    if (tid >= total) return;
    int node = tid >> 4;
    int q = tid & 15;
    float4 v;
    if (node < N_USERS)                v = uw[node * 16 + q];
    else if (node < N_USERS + N_ITEMS) v = iw[(node - N_USERS) * 16 + q];
    else                               v = tw[(node - N_USERS - N_ITEMS) * 16 + q];
    x0[tid] = v;
}

// ---------------------------------------------------------------------------
// CSR build step 1: per-row edge histogram (int atomics).
// ---------------------------------------------------------------------------
__global__ void hist_kernel(const int* __restrict__ row, int* __restrict__ cnt) {
    int e = blockIdx.x * blockDim.x + threadIdx.x;
    if (e >= NNZ) return;
    atomicAdd(&cnt[row[e]], 1);
}

// ---------------------------------------------------------------------------
// CSR build step 2a: per-block exclusive scan; emit block totals.
// ---------------------------------------------------------------------------
__global__ void scan1(const int* __restrict__ cnt,
                      int* __restrict__ rloc,
                      int* __restrict__ bsum) {
    __shared__ int wsum[16];
    const int t = threadIdx.x;
    const int lane = t & 63;
    const int wid = t >> 6;
    int i = blockIdx.x * SCAN_BLK + t;
    int v = (i < N_NODES) ? cnt[i] : 0;
    int x = v;
    #pragma unroll
    for (int off = 1; off < 64; off <<= 1) {
        int y = __shfl_up(x, off, 64);
        if (lane >= off) x += y;
    }
    if (lane == 63) wsum[wid] = x;
    __syncthreads();
    int wbase = 0;
    for (int w = 0; w < wid; ++w) wbase += wsum[w];
    int excl = wbase + (x - v);
    if (i < N_NODES) rloc[i] = excl;
    if (t == SCAN_BLK - 1) bsum[blockIdx.x] = excl + v;
}

// ---------------------------------------------------------------------------
// CSR build step 2b: exclusive scan of the 148 block totals (one block).
// ---------------------------------------------------------------------------
__global__ void scan2(const int* __restrict__ bsum, int* __restrict__ boff) {
    __shared__ int s[256];
    int t = threadIdx.x;
    int v = (t < SCAN_NBLK) ? bsum[t] : 0;
    s[t] = v;
    __syncthreads();
    for (int off = 1; off < 256; off <<= 1) {
        int y = (t >= off) ? s[t - off] : 0;
        __syncthreads();
        s[t] += y;
        __syncthreads();
    }
    if (t < SCAN_NBLK) boff[t] = s[t] - v;   // exclusive
}

// ---------------------------------------------------------------------------
// CSR build step 2c: rowptr = rloc + boff[block]; cursor = rowptr.
// ---------------------------------------------------------------------------
__global__ void scan3(const int* __restrict__ rloc,
                      const int* __restrict__ boff,
                      int* __restrict__ rowptr,
                      int* __restrict__ cursor) {
    int i = blockIdx.x * SCAN_BLK + threadIdx.x;
    if (i < N_NODES) {
        int p = rloc[i] + boff[blockIdx.x];
        rowptr[i] = p;
        cursor[i] = p;
    }
    if (i == 0) rowptr[N_NODES] = NNZ;
}

// ---------------------------------------------------------------------------
// CSR build step 3: XCD-partitioned scatter. blockIdx%8 selects a row-range
// owner group (maps to one XCD under round-robin dispatch); each group scans
// every edge chunk but scatters only rows it owns, so the 4 MB destination
// span stays resident in that XCD's L2 and partial lines merge in-cache.
// (col,val) packed into one int2 -> single 8B store per edge.
// ---------------------------------------------------------------------------
__global__ void scatter_part(const int* __restrict__ row,
                             const int* __restrict__ col,
                             const float* __restrict__ vals,
                             int* __restrict__ cursor,
                             int2* __restrict__ cv) {
    int grp = blockIdx.x & (NGRP - 1);
    int chunk = blockIdx.x >> 3;
    int e = chunk * blockDim.x + threadIdx.x;
    if (e >= NNZ) return;
    int r = row[e];
    if (r / ROWS_PER_GRP != grp) return;
    int p = atomicAdd(&cursor[r], 1);
    cv[p] = make_int2(col[e], __float_as_int(vals[e]));
}

// ---------------------------------------------------------------------------
// SpMM over CSR: one 64-lane wave per row, lane = dim. Unroll-4 gathers.
// ---------------------------------------------------------------------------
__global__ void spmm_csr(const int* __restrict__ rowptr,
                         const int2* __restrict__ cv,
                         const float* __restrict__ x,
                         float* __restrict__ y) {
    int r = blockIdx.x * (blockDim.x >> 6) + (threadIdx.x >> 6);
    int lane = threadIdx.x & 63;
    if (r >= N_NODES) return;
    int beg = rowptr[r];
    int end = rowptr[r + 1];
    float acc = 0.0f;
    int j = beg;
    for (; j + 3 < end; j += 4) {
        int2 a = cv[j];
        int2 b = cv[j + 1];
        int2 c = cv[j + 2];
        int2 d = cv[j + 3];
        float xa = x[(size_t)a.x * 64 + lane];
        float xb = x[(size_t)b.x * 64 + lane];
        float xc = x[(size_t)c.x * 64 + lane];
        float xd = x[(size_t)d.x * 64 + lane];
        acc = fmaf(__int_as_float(a.y), xa, acc);
        acc = fmaf(__int_as_float(b.y), xb, acc);
        acc = fmaf(__int_as_float(c.y), xc, acc);
        acc = fmaf(__int_as_float(d.y), xd, acc);
    }
    for (; j < end; ++j) {
        int2 a = cv[j];
        acc = fmaf(__int_as_float(a.y), x[(size_t)a.x * 64 + lane], acc);
    }
    y[(size_t)r * 64 + lane] = acc;
}

// ---------------------------------------------------------------------------
// Batch accumulator init: accb[b] = user_w[users[b]], accb[B+b] = item_w[items[b]]
// ---------------------------------------------------------------------------
__global__ void batch_init(const float4* __restrict__ uw,
                           const float4* __restrict__ iw,
                           const int* __restrict__ users,
                           const int* __restrict__ items,
                           float4* __restrict__ accb) {
    int tid = blockIdx.x * blockDim.x + threadIdx.x;   // row*16 + q
    const int total = 2 * BATCH * (DIM / 4);
    if (tid >= total) return;
    int r = tid >> 4;
    int q = tid & 15;
    float4 v;
    if (r < BATCH) v = uw[(size_t)users[r] * 16 + q];
    else           v = iw[(size_t)items[r - BATCH] * 16 + q];
    accb[tid] = v;
}

// ---------------------------------------------------------------------------
// Batch accumulator add from full node table.
// ---------------------------------------------------------------------------
__global__ void batch_add(const float4* __restrict__ emb,
                          const int* __restrict__ users,
                          const int* __restrict__ items,
                          float4* __restrict__ accb) {
    int tid = blockIdx.x * blockDim.x + threadIdx.x;
    const int total = 2 * BATCH * (DIM / 4);
    if (tid >= total) return;
    int r = tid >> 4;
    int q = tid & 15;
    int node = (r < BATCH) ? users[r] : (N_USERS + items[r - BATCH]);
    float4 v = emb[(size_t)node * 16 + q];
    float4 a = accb[tid];
    a.x += v.x; a.y += v.y; a.z += v.z; a.w += v.w;
    accb[tid] = a;
}

// ---------------------------------------------------------------------------
// Final dot: out[b] = (accb[b] . accb[BATCH+b]) / 16
// ---------------------------------------------------------------------------
__global__ void final_dot(const float* __restrict__ accb,
                          float* __restrict__ out) {
    int b = blockIdx.x * 4 + (threadIdx.x >> 6);
    int lane = threadIdx.x & 63;
    if (b >= BATCH) return;
    float pu = accb[(size_t)b * 64 + lane];
    float pi = accb[(size_t)(BATCH + b) * 64 + lane];
    float p = pu * pi;
    #pragma unroll
    for (int off = 32; off > 0; off >>= 1)
        p += __shfl_down(p, off, 64);
    if (lane == 0) out[b] = p * (1.0f / 16.0f);
}

extern "C" void kernel_launch(void* const* d_in, const int* in_sizes, int n_in,
                              void* d_out, int out_size, void* d_ws, size_t ws_size,
                              hipStream_t stream) {
    const float* uw   = (const float*)d_in[0];
    const float* iw   = (const float*)d_in[1];
    const float* tw   = (const float*)d_in[2];
    const float* vals = (const float*)d_in[3];
    const int*   row  = (const int*)d_in[4];
    const int*   col  = (const int*)d_in[5];
    const int*   users= (const int*)d_in[6];
    const int*   items= (const int*)d_in[7];
    float* out = (float*)d_out;

    // ---- workspace layout ----
    char* ws = (char*)d_ws;
    const size_t NODE_F = (size_t)N_NODES * DIM;       // 9,664,000 floats
    float* A      = (float*)ws;  ws += NODE_F * 4;
    float* B      = (float*)ws;  ws += NODE_F * 4;
    float* ACCB   = (float*)ws;  ws += (size_t)2 * BATCH * DIM * 4;
    int*   cnt    = (int*)ws;    ws += (size_t)N_NODES * 4;
    int*   rloc   = (int*)ws;    ws += (size_t)N_NODES * 4;
    int*   rowptr = (int*)ws;    ws += (size_t)(N_NODES + 1) * 4;
    int*   cursor = (int*)ws;    ws += (size_t)N_NODES * 4;
    int*   bsum   = (int*)ws;    ws += (size_t)SCAN_NBLK * 4;
    int*   boff   = (int*)ws;    ws += (size_t)SCAN_NBLK * 4;
    int2*  cv     = (int2*)ws;   ws += (size_t)NNZ * 8;

    const int node_v4  = N_NODES * (DIM / 4);
    const int batch_v4 = 2 * BATCH * (DIM / 4);

    // ---- CSR build ----
    hipMemsetAsync(cnt, 0, (size_t)N_NODES * 4, stream);
    hist_kernel<<<(NNZ + 255) / 256, 256, 0, stream>>>(row, cnt);
    scan1<<<SCAN_NBLK, SCAN_BLK, 0, stream>>>(cnt, rloc, bsum);
    scan2<<<1, 256, 0, stream>>>(bsum, boff);
    scan3<<<SCAN_NBLK, SCAN_BLK, 0, stream>>>(rloc, boff, rowptr, cursor);
    scatter_part<<<NGRP * ((NNZ + 255) / 256), 256, 0, stream>>>(
        row, col, vals, cursor, cv);

    // ---- layer-0 embedding + batch accumulator init ----
    concat_init<<<(node_v4 + 255) / 256, 256, 0, stream>>>(
        (const float4*)uw, (const float4*)iw, (const float4*)tw, (float4*)A);
    batch_init<<<(batch_v4 + 255) / 256, 256, 0, stream>>>(
        (const float4*)uw, (const float4*)iw, users, items, (float4*)ACCB);

    // ---- 3 propagation layers ----
    float* cur = A;
    float* nxt = B;
    const int spmm_blocks = (N_NODES + 3) / 4;   // 4 row-waves per 256-block
    for (int l = 0; l < 3; ++l) {
        spmm_csr<<<spmm_blocks, 256, 0, stream>>>(rowptr, cv, cur, nxt);
        batch_add<<<(batch_v4 + 255) / 256, 256, 0, stream>>>(
            (const float4*)nxt, users, items, (float4*)ACCB);
        float* t = cur; cur = nxt; nxt = t;
    }

    final_dot<<<(BATCH + 3) / 4, 256, 0, stream>>>(ACCB, out);
}